// Round 1
// baseline (65.450 us; speedup 1.0000x reference)
//
#include <hip/hip_runtime.h>
#include <hip/hip_bf16.h>

// Sizes fixed by setup_inputs()
#define N_EL   1024
#define N_UP   512
#define NNUC   256
#define DIM    256
#define EDIM   32

#define GAIN_F      1.7872135f          // 1/std(silu(N(0,1))), analytic
#define INV_SQRT2_F 0.7071067811865476f

typedef __attribute__((ext_vector_type(8))) short bf16x8;
typedef __attribute__((ext_vector_type(4))) float f32x4;

__device__ __forceinline__ short f2bf(float x) {
    union { float f; unsigned u; } v; v.f = x;
    unsigned u = v.u;
    u = (u + 0x7fffu + ((u >> 16) & 1u)) >> 16;   // RNE
    return (short)u;
}

// ---------------------------------------------------------------------------
// K0: rearrange up/down tables into MFMA C-fragment order (f32) and W_edge
// into B-fragment order (bf16).
//  tab_arr[((kt*16+dt)*64 + lane)*4 + r] = tab[kt*16 + (lane>>4)*4 + r][dt*16 + (lane&15)]
//  wedge_arr[(dt*64 + lane)*8 + b]      = bf16(W_edge[8*(lane>>4)+b][dt*16 + (lane&15)])
// ---------------------------------------------------------------------------
__global__ __launch_bounds__(256) void prep_kernel(
    const float* __restrict__ up, const float* __restrict__ dn,
    const float* __restrict__ wedge,
    float* __restrict__ tab_up, float* __restrict__ tab_dn,
    short* __restrict__ wedge_arr)
{
    const int idx = (blockIdx.x << 8) + threadIdx.x;   // 0..65535
    const int kt = idx >> 12;
    const int dt = (idx >> 8) & 15;
    const int l  = (idx >> 2) & 63;
    const int r  = idx & 3;
    const int row = (kt << 4) + ((l >> 4) << 2) + r;
    const int col = (dt << 4) + (l & 15);
    tab_up[idx] = up[row * DIM + col];
    tab_dn[idx] = dn[row * DIM + col];
    if (idx < 16 * 64 * 8) {                           // 8192 entries
        const int dt2 = idx >> 9;
        const int l2  = (idx >> 3) & 63;
        const int b   = idx & 7;
        const int j   = ((l2 >> 4) << 3) + b;
        const int d   = (dt2 << 4) + (l2 & 15);
        wedge_arr[idx] = f2bf(wedge[j * DIM + d]);
    }
}

// ---------------------------------------------------------------------------
// K1: fused edge-GEMM * spin-table * segment-sum.
// Block = 4 electrons (same spin), 4 waves. Wave w owns k-tiles 4w..4w+3.
// Per (kt,dt) tile: C = MFMA(Edge[16x32], W_edge[32x16]); lane holds
// C[row=4g+r][col=lane&15]; multiply by tab frag, reduce rows.
// agg (in d_out scratch) = scale1 * sum_k (inp * weights).
// ---------------------------------------------------------------------------
__global__ __launch_bounds__(256) void edge_kernel(
    const float* __restrict__ edge_emb,
    const float* __restrict__ tab_up, const float* __restrict__ tab_dn,
    const short* __restrict__ wedge_arr,
    const float* __restrict__ scale1_p,
    float* __restrict__ agg)
{
    __shared__ float part[4][4][256];      // [wave][e][d]
    const int tid  = threadIdx.x;
    const int w    = tid >> 6;
    const int lane = tid & 63;
    const int r15  = lane & 15;
    const int g    = lane >> 4;
    const int base = blockIdx.x << 2;      // first electron of the block
    const float* __restrict__ tab = (base < N_UP) ? tab_up : tab_dn;

    // Load A fragments: 4 electrons x 4 k-tiles, convert f32->bf16.
    // A[row=r15][j=8g+b] ; consistent with B's (g,b)->j mapping -> layout-robust.
    bf16x8 a[4][4];
    #pragma unroll
    for (int e = 0; e < 4; ++e) {
        #pragma unroll
        for (int q = 0; q < 4; ++q) {
            const int kt = (w << 2) + q;
            const float* src = edge_emb +
                ((size_t)((base + e) * NNUC + (kt << 4) + r15) * EDIM + (g << 3));
            f32x4 lo = *(const f32x4*)(src);
            f32x4 hi = *(const f32x4*)(src + 4);
            bf16x8 f;
            f[0] = f2bf(lo[0]); f[1] = f2bf(lo[1]);
            f[2] = f2bf(lo[2]); f[3] = f2bf(lo[3]);
            f[4] = f2bf(hi[0]); f[5] = f2bf(hi[1]);
            f[6] = f2bf(hi[2]); f[7] = f2bf(hi[3]);
            a[e][q] = f;
        }
    }

    const int kt0 = (w << 2);
    // software prefetch of next-dt operands (only 4 waves/CU -> hide L2 latency)
    bf16x8 bnxt = *(const bf16x8*)(wedge_arr + (lane << 3));               // dt=0
    f32x4 tn0 = *(const f32x4*)(tab + ((((kt0 + 0) << 4) + 0 << 0) * 0));  // placeholder, re-set below
    f32x4 tn1, tn2, tn3;
    {
        tn0 = *(const f32x4*)(tab + ((((kt0 + 0) << 4) + 0) * 64 + lane) * 4);
        tn1 = *(const f32x4*)(tab + ((((kt0 + 1) << 4) + 0) * 64 + lane) * 4);
        tn2 = *(const f32x4*)(tab + ((((kt0 + 2) << 4) + 0) * 64 + lane) * 4);
        tn3 = *(const f32x4*)(tab + ((((kt0 + 3) << 4) + 0) * 64 + lane) * 4);
    }

    const f32x4 zero4 = {0.f, 0.f, 0.f, 0.f};

    #pragma unroll 1
    for (int dt = 0; dt < 16; ++dt) {
        const bf16x8 bcur = bnxt;
        const f32x4 t0 = tn0, t1 = tn1, t2 = tn2, t3 = tn3;
        if (dt < 15) {
            bnxt = *(const bf16x8*)(wedge_arr + (((dt + 1) << 6) + lane) * 8);
            tn0 = *(const f32x4*)(tab + ((((kt0 + 0) << 4) + dt + 1) * 64 + lane) * 4);
            tn1 = *(const f32x4*)(tab + ((((kt0 + 1) << 4) + dt + 1) * 64 + lane) * 4);
            tn2 = *(const f32x4*)(tab + ((((kt0 + 2) << 4) + dt + 1) * 64 + lane) * 4);
            tn3 = *(const f32x4*)(tab + ((((kt0 + 3) << 4) + dt + 1) * 64 + lane) * 4);
        }
        float p[4] = {0.f, 0.f, 0.f, 0.f};
        #pragma unroll
        for (int e = 0; e < 4; ++e) {
            f32x4 c;
            c = __builtin_amdgcn_mfma_f32_16x16x32_bf16(a[e][0], bcur, zero4, 0, 0, 0);
            p[e] += c[0] * t0[0] + c[1] * t0[1] + c[2] * t0[2] + c[3] * t0[3];
            c = __builtin_amdgcn_mfma_f32_16x16x32_bf16(a[e][1], bcur, zero4, 0, 0, 0);
            p[e] += c[0] * t1[0] + c[1] * t1[1] + c[2] * t1[2] + c[3] * t1[3];
            c = __builtin_amdgcn_mfma_f32_16x16x32_bf16(a[e][2], bcur, zero4, 0, 0, 0);
            p[e] += c[0] * t2[0] + c[1] * t2[1] + c[2] * t2[2] + c[3] * t2[3];
            c = __builtin_amdgcn_mfma_f32_16x16x32_bf16(a[e][3], bcur, zero4, 0, 0, 0);
            p[e] += c[0] * t3[0] + c[1] * t3[1] + c[2] * t3[2] + c[3] * t3[3];
        }
        #pragma unroll
        for (int e = 0; e < 4; ++e) {
            float v = p[e];
            v += __shfl_xor(v, 16, 64);
            v += __shfl_xor(v, 32, 64);
            if (lane < 16) part[w][e][(dt << 4) + lane] = v;
        }
    }
    __syncthreads();

    const float s1 = *scale1_p;
    for (int t = tid; t < 4 * 256; t += 256) {
        const int e = t >> 8;
        const int d = t & 255;
        const float s = part[0][e][d] + part[1][e][d] + part[2][e][d] + part[3][e][d];
        agg[(size_t)(base + e) * DIM + d] = s * s1;
    }
}

// ---------------------------------------------------------------------------
// K2: per-4-rows fused: out1 = elec@W1 + b1; y = (out1 + agg*norm)*scale2;
// h = act(y); z = h@W2 + b2; out = (elec + act(z)) * inv_sqrt2.  All f32.
// agg lives in d_out; each block reads its own rows before overwriting them.
// ---------------------------------------------------------------------------
__global__ __launch_bounds__(256) void out_kernel(
    const float* __restrict__ elec,
    const float* __restrict__ agg,
    const float* __restrict__ norm,
    const float* __restrict__ W1, const float* __restrict__ b1,
    const float* __restrict__ W2, const float* __restrict__ b2,
    const float* __restrict__ scale2_p,
    float* __restrict__ outp)
{
    __shared__ float es[4][256];
    __shared__ float hs[4][256];
    const int tid  = threadIdx.x;
    const int base = blockIdx.x << 2;

    for (int t = tid; t < 1024; t += 256)
        es[t >> 8][t & 255] = elec[((size_t)base << 8) + t];
    __syncthreads();

    const int d = tid;
    const float s2 = *scale2_p;

    float acc0, acc1, acc2, acc3;
    {
        const float bv = b1[d];
        acc0 = bv; acc1 = bv; acc2 = bv; acc3 = bv;
    }
    #pragma unroll 4
    for (int k = 0; k < 256; ++k) {
        const float wv = W1[k * DIM + d];
        acc0 += es[0][k] * wv;
        acc1 += es[1][k] * wv;
        acc2 += es[2][k] * wv;
        acc3 += es[3][k] * wv;
    }
    {
        float accs[4] = {acc0, acc1, acc2, acc3};
        #pragma unroll
        for (int r = 0; r < 4; ++r) {
            const float nv = norm[base + r];
            const float av = agg[(size_t)(base + r) * DIM + d];
            const float y  = (accs[r] + av * nv) * s2;
            const float sig = 1.f / (1.f + __expf(-y));
            hs[r][d] = GAIN_F * y * sig;
        }
    }
    __syncthreads();

    float z0, z1, z2, z3;
    {
        const float bv = b2[d];
        z0 = bv; z1 = bv; z2 = bv; z3 = bv;
    }
    #pragma unroll 4
    for (int k = 0; k < 256; ++k) {
        const float wv = W2[k * DIM + d];
        z0 += hs[0][k] * wv;
        z1 += hs[1][k] * wv;
        z2 += hs[2][k] * wv;
        z3 += hs[3][k] * wv;
    }
    {
        float zs[4] = {z0, z1, z2, z3};
        #pragma unroll
        for (int r = 0; r < 4; ++r) {
            const float zz  = zs[r];
            const float sig = 1.f / (1.f + __expf(-zz));
            const float o   = GAIN_F * zz * sig;
            outp[(size_t)(base + r) * DIM + d] = (es[r][d] + o) * INV_SQRT2_F;
        }
    }
}

// ---------------------------------------------------------------------------
extern "C" void kernel_launch(void* const* d_in, const int* in_sizes, int n_in,
                              void* d_out, int out_size, void* d_ws, size_t ws_size,
                              hipStream_t stream)
{
    const float* elec  = (const float*)d_in[0];
    const float* up    = (const float*)d_in[1];
    const float* dn    = (const float*)d_in[2];
    const float* eemb  = (const float*)d_in[3];
    // d_in[4] = contr: init-time only, unused at runtime
    const float* norm  = (const float*)d_in[5];
    const float* W1    = (const float*)d_in[6];
    const float* b1    = (const float*)d_in[7];
    const float* Wedge = (const float*)d_in[8];
    const float* W2    = (const float*)d_in[9];
    const float* b2    = (const float*)d_in[10];
    const float* s1    = (const float*)d_in[11];
    const float* s2    = (const float*)d_in[12];

    // ws layout: tab_up (256KB) | tab_dn (256KB) | wedge_arr (16KB)  = 528KB
    float* ws     = (float*)d_ws;
    float* tab_up = ws;
    float* tab_dn = ws + 65536;
    short* warr   = (short*)(ws + 131072);
    float* agg    = (float*)d_out;   // d_out doubles as agg scratch (fully rewritten)

    prep_kernel<<<256, 256, 0, stream>>>(up, dn, Wedge, tab_up, tab_dn, warr);
    edge_kernel<<<256, 256, 0, stream>>>(eemb, tab_up, tab_dn, warr, s1, agg);
    out_kernel <<<256, 256, 0, stream>>>(elec, agg, norm, W1, b1, W2, b2, s2, (float*)d_out);
}

// Round 2
// 34.274 us; speedup vs baseline: 1.9096x; 1.9096x over previous
//
#include <hip/hip_runtime.h>
#include <hip/hip_bf16.h>

// Sizes fixed by setup_inputs()
#define N_EL   1024
#define N_UP   512
#define NNUC   256
#define DIM    256
#define EDIM   32

#define GAIN_F      1.7872135f          // 1/std(silu(N(0,1))), analytic
#define INV_SQRT2_F 0.7071067811865476f

typedef __attribute__((ext_vector_type(8))) short bf16x8;
typedef __attribute__((ext_vector_type(4))) short bf16x4;
typedef __attribute__((ext_vector_type(4))) float f32x4;

__device__ __forceinline__ short f2bf(float x) {
    union { float f; unsigned u; } v; v.f = x;
    unsigned u = v.u;
    u = (u + 0x7fffu + ((u >> 16) & 1u)) >> 16;   // RNE
    return (short)u;
}

// ---------------------------------------------------------------------------
// K0 prep: all layout rearrangement + f32->bf16 conversion, one pass.
//  tab_arr[((kt*16+dt)*64 + l)*4 + r] = tab[kt*16 + (l>>4)*4 + r][dt*16 + (l&15)]   (f32)
//  wedge_arr[(dt*64 + l)*8 + b]      = bf16(W_edge[8*(l>>4)+b][dt*16 + (l&15)])
//  wf[((nt*8+q)*64 + l)*8 + b]       = bf16(W[q*32 + 8*(l>>4) + b][nt*16 + (l&15)])  (B-frag)
//  elecb[i]                          = bf16(elec[i])                                  (row-major)
// ---------------------------------------------------------------------------
__global__ __launch_bounds__(256) void prep_kernel(
    const float* __restrict__ up, const float* __restrict__ dn,
    const float* __restrict__ wedge,
    const float* __restrict__ w1, const float* __restrict__ w2,
    const float* __restrict__ elec,
    float* __restrict__ tab_up, float* __restrict__ tab_dn,
    short* __restrict__ wedge_arr,
    short* __restrict__ w1f, short* __restrict__ w2f,
    short* __restrict__ elecb)
{
    const int idx = (blockIdx.x << 8) + threadIdx.x;   // 0..65535

    { // spin tables -> C-fragment order (f32)
        const int kt = idx >> 12;
        const int dt = (idx >> 8) & 15;
        const int l  = (idx >> 2) & 63;
        const int r  = idx & 3;
        const int row = (kt << 4) + ((l >> 4) << 2) + r;
        const int col = (dt << 4) + (l & 15);
        tab_up[idx] = up[row * DIM + col];
        tab_dn[idx] = dn[row * DIM + col];
    }
    if (idx < 16 * 64 * 8) {                           // W_edge B-frag (8192)
        const int dt2 = idx >> 9;
        const int l2  = (idx >> 3) & 63;
        const int b   = idx & 7;
        const int j   = ((l2 >> 4) << 3) + b;
        const int d   = (dt2 << 4) + (l2 & 15);
        wedge_arr[idx] = f2bf(wedge[j * DIM + d]);
    }
    { // W1/W2 -> B-frag bf16 (65536 each)
        const int b  = idx & 7;
        const int l  = (idx >> 3) & 63;
        const int q  = (idx >> 9) & 7;
        const int nt = idx >> 12;
        const int j  = (q << 5) + ((l >> 4) << 3) + b;   // k index
        const int d  = (nt << 4) + (l & 15);             // col index
        w1f[idx] = f2bf(w1[j * DIM + d]);
        w2f[idx] = f2bf(w2[j * DIM + d]);
    }
    { // elec -> row-major bf16, 4 elems/thread
        const f32x4 v = *(const f32x4*)(elec + (idx << 2));
        bf16x4 o;
        o[0] = f2bf(v[0]); o[1] = f2bf(v[1]); o[2] = f2bf(v[2]); o[3] = f2bf(v[3]);
        *(bf16x4*)(elecb + (idx << 2)) = o;
    }
}

// ---------------------------------------------------------------------------
// K1: fused edge-GEMM * spin-table * segment-sum (unchanged from R1).
// agg (in d_out scratch) = scale1 * sum_k (inp * weights).
// ---------------------------------------------------------------------------
__global__ __launch_bounds__(256) void edge_kernel(
    const float* __restrict__ edge_emb,
    const float* __restrict__ tab_up, const float* __restrict__ tab_dn,
    const short* __restrict__ wedge_arr,
    const float* __restrict__ scale1_p,
    float* __restrict__ agg)
{
    __shared__ float part[4][4][256];      // [wave][e][d]
    const int tid  = threadIdx.x;
    const int w    = tid >> 6;
    const int lane = tid & 63;
    const int r15  = lane & 15;
    const int g    = lane >> 4;
    const int base = blockIdx.x << 2;      // first electron of the block
    const float* __restrict__ tab = (base < N_UP) ? tab_up : tab_dn;

    bf16x8 a[4][4];
    #pragma unroll
    for (int e = 0; e < 4; ++e) {
        #pragma unroll
        for (int q = 0; q < 4; ++q) {
            const int kt = (w << 2) + q;
            const float* src = edge_emb +
                ((size_t)((base + e) * NNUC + (kt << 4) + r15) * EDIM + (g << 3));
            f32x4 lo = *(const f32x4*)(src);
            f32x4 hi = *(const f32x4*)(src + 4);
            bf16x8 f;
            f[0] = f2bf(lo[0]); f[1] = f2bf(lo[1]);
            f[2] = f2bf(lo[2]); f[3] = f2bf(lo[3]);
            f[4] = f2bf(hi[0]); f[5] = f2bf(hi[1]);
            f[6] = f2bf(hi[2]); f[7] = f2bf(hi[3]);
            a[e][q] = f;
        }
    }

    const int kt0 = (w << 2);
    bf16x8 bnxt = *(const bf16x8*)(wedge_arr + (lane << 3));               // dt=0
    f32x4 tn0, tn1, tn2, tn3;
    tn0 = *(const f32x4*)(tab + ((((kt0 + 0) << 4) + 0) * 64 + lane) * 4);
    tn1 = *(const f32x4*)(tab + ((((kt0 + 1) << 4) + 0) * 64 + lane) * 4);
    tn2 = *(const f32x4*)(tab + ((((kt0 + 2) << 4) + 0) * 64 + lane) * 4);
    tn3 = *(const f32x4*)(tab + ((((kt0 + 3) << 4) + 0) * 64 + lane) * 4);

    const f32x4 zero4 = {0.f, 0.f, 0.f, 0.f};

    #pragma unroll 1
    for (int dt = 0; dt < 16; ++dt) {
        const bf16x8 bcur = bnxt;
        const f32x4 t0 = tn0, t1 = tn1, t2 = tn2, t3 = tn3;
        if (dt < 15) {
            bnxt = *(const bf16x8*)(wedge_arr + (((dt + 1) << 6) + lane) * 8);
            tn0 = *(const f32x4*)(tab + ((((kt0 + 0) << 4) + dt + 1) * 64 + lane) * 4);
            tn1 = *(const f32x4*)(tab + ((((kt0 + 1) << 4) + dt + 1) * 64 + lane) * 4);
            tn2 = *(const f32x4*)(tab + ((((kt0 + 2) << 4) + dt + 1) * 64 + lane) * 4);
            tn3 = *(const f32x4*)(tab + ((((kt0 + 3) << 4) + dt + 1) * 64 + lane) * 4);
        }
        float p[4] = {0.f, 0.f, 0.f, 0.f};
        #pragma unroll
        for (int e = 0; e < 4; ++e) {
            f32x4 c;
            c = __builtin_amdgcn_mfma_f32_16x16x32_bf16(a[e][0], bcur, zero4, 0, 0, 0);
            p[e] += c[0] * t0[0] + c[1] * t0[1] + c[2] * t0[2] + c[3] * t0[3];
            c = __builtin_amdgcn_mfma_f32_16x16x32_bf16(a[e][1], bcur, zero4, 0, 0, 0);
            p[e] += c[0] * t1[0] + c[1] * t1[1] + c[2] * t1[2] + c[3] * t1[3];
            c = __builtin_amdgcn_mfma_f32_16x16x32_bf16(a[e][2], bcur, zero4, 0, 0, 0);
            p[e] += c[0] * t2[0] + c[1] * t2[1] + c[2] * t2[2] + c[3] * t2[3];
            c = __builtin_amdgcn_mfma_f32_16x16x32_bf16(a[e][3], bcur, zero4, 0, 0, 0);
            p[e] += c[0] * t3[0] + c[1] * t3[1] + c[2] * t3[2] + c[3] * t3[3];
        }
        #pragma unroll
        for (int e = 0; e < 4; ++e) {
            float v = p[e];
            v += __shfl_xor(v, 16, 64);
            v += __shfl_xor(v, 32, 64);
            if (lane < 16) part[w][e][(dt << 4) + lane] = v;
        }
    }
    __syncthreads();

    const float s1 = *scale1_p;
    for (int t = tid; t < 4 * 256; t += 256) {
        const int e = t >> 8;
        const int d = t & 255;
        const float s = part[0][e][d] + part[1][e][d] + part[2][e][d] + part[3][e][d];
        agg[(size_t)(base + e) * DIM + d] = s * s1;
    }
}

// ---------------------------------------------------------------------------
// K2 gemm1: h = act((elec@W1 + b1 + agg*norm) * scale2), stored bf16 row-major.
// Wave = one 16x16 output tile, K=256 = 8 MFMAs. Block = 4 col-adjacent tiles.
// Grid = 64 row-tiles * 4 = 256 blocks.
// C-frag (m89): row = 4*(lane>>4)+r, col = lane&15.
// ---------------------------------------------------------------------------
__global__ __launch_bounds__(256) void gemm1_kernel(
    const short* __restrict__ elecb, const short* __restrict__ w1f,
    const float* __restrict__ agg, const float* __restrict__ norm,
    const float* __restrict__ b1, const float* __restrict__ scale2_p,
    short* __restrict__ hb)
{
    const int tid  = threadIdx.x;
    const int w    = tid >> 6;
    const int lane = tid & 63;
    const int g    = lane >> 4;
    const int c    = lane & 15;
    const int mt   = blockIdx.x >> 2;
    const int nt   = ((blockIdx.x & 3) << 2) + w;

    const short* abase = elecb + (((mt << 4) + c) << 8) + (g << 3);
    const short* bbase = w1f + (nt << 12) + (lane << 3);
    bf16x8 a[8], b[8];
    #pragma unroll
    for (int q = 0; q < 8; ++q) {
        a[q] = *(const bf16x8*)(abase + (q << 5));
        b[q] = *(const bf16x8*)(bbase + (q << 9));
    }
    f32x4 acc = {0.f, 0.f, 0.f, 0.f};
    #pragma unroll
    for (int q = 0; q < 8; ++q)
        acc = __builtin_amdgcn_mfma_f32_16x16x32_bf16(a[q], b[q], acc, 0, 0, 0);

    const int n  = (nt << 4) + c;
    const float bv = b1[n];
    const float s2 = *scale2_p;
    #pragma unroll
    for (int r = 0; r < 4; ++r) {
        const int m = (mt << 4) + (g << 2) + r;
        const float y = (acc[r] + bv + agg[(m << 8) + n] * norm[m]) * s2;
        const float sig = 1.f / (1.f + __expf(-y));
        hb[(m << 8) + n] = f2bf(GAIN_F * y * sig);
    }
}

// ---------------------------------------------------------------------------
// K3 gemm2: out = (elec + act(h@W2 + b2)) * inv_sqrt2.
// ---------------------------------------------------------------------------
__global__ __launch_bounds__(256) void gemm2_kernel(
    const short* __restrict__ hb, const short* __restrict__ w2f,
    const float* __restrict__ elec, const float* __restrict__ b2,
    float* __restrict__ outp)
{
    const int tid  = threadIdx.x;
    const int w    = tid >> 6;
    const int lane = tid & 63;
    const int g    = lane >> 4;
    const int c    = lane & 15;
    const int mt   = blockIdx.x >> 2;
    const int nt   = ((blockIdx.x & 3) << 2) + w;

    const short* abase = hb + (((mt << 4) + c) << 8) + (g << 3);
    const short* bbase = w2f + (nt << 12) + (lane << 3);
    bf16x8 a[8], b[8];
    #pragma unroll
    for (int q = 0; q < 8; ++q) {
        a[q] = *(const bf16x8*)(abase + (q << 5));
        b[q] = *(const bf16x8*)(bbase + (q << 9));
    }
    f32x4 acc = {0.f, 0.f, 0.f, 0.f};
    #pragma unroll
    for (int q = 0; q < 8; ++q)
        acc = __builtin_amdgcn_mfma_f32_16x16x32_bf16(a[q], b[q], acc, 0, 0, 0);

    const int n  = (nt << 4) + c;
    const float bv = b2[n];
    #pragma unroll
    for (int r = 0; r < 4; ++r) {
        const int m = (mt << 4) + (g << 2) + r;
        const float z = acc[r] + bv;
        const float sig = 1.f / (1.f + __expf(-z));
        const float o = GAIN_F * z * sig;
        outp[(m << 8) + n] = (elec[(m << 8) + n] + o) * INV_SQRT2_F;
    }
}

// ---------------------------------------------------------------------------
extern "C" void kernel_launch(void* const* d_in, const int* in_sizes, int n_in,
                              void* d_out, int out_size, void* d_ws, size_t ws_size,
                              hipStream_t stream)
{
    const float* elec  = (const float*)d_in[0];
    const float* up    = (const float*)d_in[1];
    const float* dn    = (const float*)d_in[2];
    const float* eemb  = (const float*)d_in[3];
    // d_in[4] = contr: init-time only, unused at runtime
    const float* norm  = (const float*)d_in[5];
    const float* W1    = (const float*)d_in[6];
    const float* b1    = (const float*)d_in[7];
    const float* Wedge = (const float*)d_in[8];
    const float* W2    = (const float*)d_in[9];
    const float* b2    = (const float*)d_in[10];
    const float* s1    = (const float*)d_in[11];
    const float* s2    = (const float*)d_in[12];

    // ws layout: tab_up 65536 f32 | tab_dn 65536 f32 | then shorts:
    //   wedge_arr 8192 | w1f 65536 | w2f 65536 | elecb 262144 | hb 262144
    float* ws     = (float*)d_ws;
    float* tab_up = ws;
    float* tab_dn = ws + 65536;
    short* sbase  = (short*)(ws + 131072);
    short* warr   = sbase;
    short* w1f    = sbase + 8192;
    short* w2f    = sbase + 8192 + 65536;
    short* elecb  = sbase + 8192 + 131072;
    short* hb     = sbase + 8192 + 131072 + 262144;
    float* agg    = (float*)d_out;   // d_out doubles as agg scratch (rewritten by gemm2)

    prep_kernel <<<256, 256, 0, stream>>>(up, dn, Wedge, W1, W2, elec,
                                          tab_up, tab_dn, warr, w1f, w2f, elecb);
    edge_kernel <<<256, 256, 0, stream>>>(eemb, tab_up, tab_dn, warr, s1, agg);
    gemm1_kernel<<<256, 256, 0, stream>>>(elecb, w1f, agg, norm, b1, s2, hb);
    gemm2_kernel<<<256, 256, 0, stream>>>(hb, w2f, elec, b2, (float*)d_out);
}